// Round 1
// baseline (308.466 us; speedup 1.0000x reference)
//
#include <hip/hip_runtime.h>
#include <hip/hip_bf16.h>

typedef __bf16 bf16x8 __attribute__((ext_vector_type(8)));
typedef float  f32x4  __attribute__((ext_vector_type(4)));

// tanh-approx gelu (matches jax.nn.gelu approximate=True):
// gelu(x) = x * sigmoid(2*sqrt(2/pi)*(x + 0.044715 x^3))
__device__ __forceinline__ float gelu_tanh(float x) {
    float x2  = x * x;
    float t   = fmaf(0.044715f, x2, 1.0f);
    float arg = -1.5957691216057308f * x * t;   // -2*sqrt(2/pi)*x*(1+0.044715x^2)
    float e   = __expf(arg);
    return x * __builtin_amdgcn_rcpf(1.0f + e);
}

// W2 (128x256 f32, row-major) -> w2t bf16 [u][k] = W2[k][u], K-contiguous per column
__global__ void prep_w2t(const float* __restrict__ W2, __bf16* __restrict__ w2t) {
    int idx = blockIdx.x * 256 + threadIdx.x;
    if (idx >= 128 * 256) return;
    int k = idx >> 8;
    int u = idx & 255;
    w2t[u * 128 + k] = (__bf16)W2[idx];
}

__launch_bounds__(256, 2)
__global__ void edge_mlp(const float* __restrict__ y, const float* __restrict__ x,
                         const float* __restrict__ fy,
                         const int* __restrict__ nbr, const int* __restrict__ xidx,
                         const float* __restrict__ W1, const float* __restrict__ b1,
                         const __bf16* __restrict__ w2t, const float* __restrict__ b2,
                         const float* __restrict__ W3, const float* __restrict__ b3,
                         float* __restrict__ out, int E) {
    __shared__ __attribute__((aligned(16))) __bf16 Atile[64 * 128]; // 16 KB, XOR-swizzled
    __shared__ float rels[64][3];
    __shared__ float fys[64][3];
    __shared__ int   is[64];
    __shared__ float out3[64 * 3];

    const int tid  = threadIdx.x;
    const int base = blockIdx.x * 64;

    // ---- load edge tile ----
    if (tid < 64) {
        int g = base + tid;
        if (g < E) {
            int j = nbr[g];
            int i = xidx[g];
            is[tid] = i;
            rels[tid][0] = y[j*3+0] - x[i*3+0];
            rels[tid][1] = y[j*3+1] - x[i*3+1];
            rels[tid][2] = y[j*3+2] - x[i*3+2];
            fys[tid][0] = fy[j*3+0];
            fys[tid][1] = fy[j*3+1];
            fys[tid][2] = fy[j*3+2];
        } else {
            is[tid] = -1;
            rels[tid][0] = rels[tid][1] = rels[tid][2] = 0.0f;
            fys[tid][0] = fys[tid][1] = fys[tid][2] = 0.0f;
        }
    }
    if (tid < 192) out3[tid] = 0.0f;
    __syncthreads();

    // ---- layer 1: h1 = gelu(rel @ W1 + b1), write bf16 A-tile (swizzled) ----
    {
        int u  = tid & 127;           // constant per thread
        int e0 = tid >> 7;
        float w0 = W1[u], w1 = W1[128 + u], w2 = W1[256 + u], bb = b1[u];
        #pragma unroll
        for (int r = 0; r < 32; ++r) {
            int e = e0 + 2 * r;
            float pre = fmaf(rels[e][0], w0, fmaf(rels[e][1], w1, fmaf(rels[e][2], w2, bb)));
            float g = gelu_tanh(pre);
            int elem = (e * 128 + u) ^ ((e & 7) << 3);
            Atile[elem] = (__bf16)g;
        }
    }
    __syncthreads();

    // ---- layer 2 MFMA: [64 x 128] @ [128 x 256], wave w owns cols [64w, 64w+64) ----
    const int w    = tid >> 6;
    const int lane = tid & 63;
    const int l15  = lane & 15;
    const int lhi  = lane >> 4;

    f32x4 acc[4][4];
    #pragma unroll
    for (int mt = 0; mt < 4; ++mt)
        #pragma unroll
        for (int nt = 0; nt < 4; ++nt)
            acc[mt][nt] = (f32x4){0.0f, 0.0f, 0.0f, 0.0f};

    #pragma unroll
    for (int ks = 0; ks < 4; ++ks) {
        int kb = ks * 32 + lhi * 8;
        bf16x8 af[4], bfr[4];
        #pragma unroll
        for (int mt = 0; mt < 4; ++mt) {
            int row = mt * 16 + l15;
            af[mt] = *(const bf16x8*)&Atile[(row * 128 + kb) ^ ((row & 7) << 3)];
        }
        #pragma unroll
        for (int nt = 0; nt < 4; ++nt) {
            int u = w * 64 + nt * 16 + l15;
            bfr[nt] = *(const bf16x8*)&w2t[u * 128 + kb];   // from L2
        }
        #pragma unroll
        for (int mt = 0; mt < 4; ++mt)
            #pragma unroll
            for (int nt = 0; nt < 4; ++nt)
                acc[mt][nt] = __builtin_amdgcn_mfma_f32_16x16x32_bf16(af[mt], bfr[nt], acc[mt][nt], 0, 0, 0);
    }

    // ---- epilogue: gelu(h2 + b2), fold layer 3 (256->3) via per-lane partials ----
    float part[4][4][3];
    #pragma unroll
    for (int mt = 0; mt < 4; ++mt)
        #pragma unroll
        for (int rg = 0; rg < 4; ++rg)
            part[mt][rg][0] = part[mt][rg][1] = part[mt][rg][2] = 0.0f;

    #pragma unroll
    for (int nt = 0; nt < 4; ++nt) {
        int u = w * 64 + nt * 16 + l15;
        float b2u = b2[u];
        float w30 = W3[u*3+0], w31 = W3[u*3+1], w32 = W3[u*3+2];
        #pragma unroll
        for (int mt = 0; mt < 4; ++mt) {
            #pragma unroll
            for (int rg = 0; rg < 4; ++rg) {
                float h = acc[mt][nt][rg] + b2u;
                float g = gelu_tanh(h);
                part[mt][rg][0] = fmaf(g, w30, part[mt][rg][0]);
                part[mt][rg][1] = fmaf(g, w31, part[mt][rg][1]);
                part[mt][rg][2] = fmaf(g, w32, part[mt][rg][2]);
            }
        }
    }

    // reduce over the 16 lanes that share lhi (they hold different u, same e-rows)
    #pragma unroll
    for (int m = 1; m <= 8; m <<= 1) {
        #pragma unroll
        for (int mt = 0; mt < 4; ++mt)
            #pragma unroll
            for (int rg = 0; rg < 4; ++rg) {
                part[mt][rg][0] += __shfl_xor(part[mt][rg][0], m, 64);
                part[mt][rg][1] += __shfl_xor(part[mt][rg][1], m, 64);
                part[mt][rg][2] += __shfl_xor(part[mt][rg][2], m, 64);
            }
    }
    if (l15 == 0) {
        #pragma unroll
        for (int mt = 0; mt < 4; ++mt)
            #pragma unroll
            for (int rg = 0; rg < 4; ++rg) {
                int e = mt * 16 + lhi * 4 + rg;
                atomicAdd(&out3[e*3+0], part[mt][rg][0]);
                atomicAdd(&out3[e*3+1], part[mt][rg][1]);
                atomicAdd(&out3[e*3+2], part[mt][rg][2]);
            }
    }
    __syncthreads();

    // ---- finalize: msg = (out3 + b3) * f_y[j], accumulate into global out ----
    if (tid < 64) {
        int i = is[tid];
        if (i >= 0) {
            float b30 = b3[0], b31 = b3[1], b32 = b3[2];
            unsafeAtomicAdd(&out[i*3+0], (out3[tid*3+0] + b30) * fys[tid][0]);
            unsafeAtomicAdd(&out[i*3+1], (out3[tid*3+1] + b31) * fys[tid][1]);
            unsafeAtomicAdd(&out[i*3+2], (out3[tid*3+2] + b32) * fys[tid][2]);
        }
    }
}

// out[i] /= max(cnt_i, 1); cnt via binary search on sorted x_index
__global__ void finalize_div(float* __restrict__ out, const int* __restrict__ xidx,
                             int E, int nx) {
    int i = blockIdx.x * blockDim.x + threadIdx.x;
    if (i >= nx) return;
    int lo = 0, hi = E;
    while (lo < hi) { int mid = (lo + hi) >> 1; if (xidx[mid] < i) lo = mid + 1; else hi = mid; }
    int start = lo;
    hi = E;
    while (lo < hi) { int mid = (lo + hi) >> 1; if (xidx[mid] < i + 1) lo = mid + 1; else hi = mid; }
    int cnt = lo - start;
    float inv = 1.0f / (float)(cnt > 1 ? cnt : 1);
    out[i*3+0] *= inv;
    out[i*3+1] *= inv;
    out[i*3+2] *= inv;
}

extern "C" void kernel_launch(void* const* d_in, const int* in_sizes, int n_in,
                              void* d_out, int out_size, void* d_ws, size_t ws_size,
                              hipStream_t stream) {
    const float* y   = (const float*)d_in[0];
    const float* x   = (const float*)d_in[1];
    const float* fyp = (const float*)d_in[2];
    const int*   nbr = (const int*)d_in[3];
    const int*   xix = (const int*)d_in[4];
    const float* W1  = (const float*)d_in[5];
    const float* b1  = (const float*)d_in[6];
    const float* W2  = (const float*)d_in[7];
    const float* b2  = (const float*)d_in[8];
    const float* W3  = (const float*)d_in[9];
    const float* b3  = (const float*)d_in[10];
    float* out = (float*)d_out;

    int E  = in_sizes[3];
    int nx = in_sizes[1] / 3;
    __bf16* w2t = (__bf16*)d_ws;

    hipMemsetAsync(d_out, 0, (size_t)out_size * sizeof(float), stream);
    prep_w2t<<<128, 256, 0, stream>>>(W2, w2t);

    int ntiles = (E + 63) / 64;
    edge_mlp<<<ntiles, 256, 0, stream>>>(y, x, fyp, nbr, xix, W1, b1, w2t, b2, W3, b3, out, E);

    finalize_div<<<(nx + 255) / 256, 256, 0, stream>>>(out, xix, E, nx);
}

// Round 2
// 190.936 us; speedup vs baseline: 1.6155x; 1.6155x over previous
//
#include <hip/hip_runtime.h>
#include <hip/hip_bf16.h>

typedef __bf16 bf16x8 __attribute__((ext_vector_type(8)));
typedef float  f32x4  __attribute__((ext_vector_type(4)));

// tanh-approx gelu (matches jax.nn.gelu approximate=True):
// gelu(x) = x * sigmoid(2*sqrt(2/pi)*(x + 0.044715 x^3))
__device__ __forceinline__ float gelu_tanh(float x) {
    float x2  = x * x;
    float t   = fmaf(0.044715f, x2, 1.0f);
    float arg = -1.5957691216057308f * x * t;   // -2*sqrt(2/pi)*x*(1+0.044715x^2)
    float e   = __expf(arg);
    return x * __builtin_amdgcn_rcpf(1.0f + e);
}

// w2t[u][k] = W2[k][u]  (bf16, K-contiguous per output column), 32768 elems
// w3t[d][u] = W3[u][d] for d<3 else 0 (bf16, padded to 16 cols), 4096 elems
__global__ void prep_weights(const float* __restrict__ W2, const float* __restrict__ W3,
                             __bf16* __restrict__ w2t, __bf16* __restrict__ w3t) {
    int idx = blockIdx.x * 256 + threadIdx.x;
    if (idx < 128 * 256) {
        int k = idx >> 8;
        int u = idx & 255;
        w2t[u * 128 + k] = (__bf16)W2[idx];
    } else if (idx < 128 * 256 + 16 * 256) {
        int t = idx - 128 * 256;
        int d = t >> 8;
        int u = t & 255;
        w3t[t] = (__bf16)(d < 3 ? W3[u * 3 + d] : 0.0f);
    }
}

__launch_bounds__(256, 4)
__global__ void edge_mlp(const float* __restrict__ y, const float* __restrict__ x,
                         const float* __restrict__ fy,
                         const int* __restrict__ nbr, const int* __restrict__ xidx,
                         const float* __restrict__ W1, const float* __restrict__ b1,
                         const __bf16* __restrict__ w2t, const float* __restrict__ b2,
                         const __bf16* __restrict__ w3t, const float* __restrict__ b3,
                         float* __restrict__ out, int E) {
    // g2s doubles as the layer-1 A-tile (first 16KB) and the gelu'd h2 tile (32KB)
    __shared__ __attribute__((aligned(16))) __bf16 g2s[64 * 256];
    __shared__ float rels[64][3];
    __shared__ float fys[64][3];
    __shared__ int   is[64];
    __shared__ float b2s[256];
    __shared__ float out3w[4][64][3];
    __shared__ float msg3[64][3];

    const int tid  = threadIdx.x;
    const int base = blockIdx.x * 64;

    // ---- stage edge tile + b2 ----
    if (tid < 64) {
        int g = base + tid;
        if (g < E) {
            int j = nbr[g];
            int i = xidx[g];
            is[tid] = i;
            rels[tid][0] = y[j*3+0] - x[i*3+0];
            rels[tid][1] = y[j*3+1] - x[i*3+1];
            rels[tid][2] = y[j*3+2] - x[i*3+2];
            fys[tid][0] = fy[j*3+0];
            fys[tid][1] = fy[j*3+1];
            fys[tid][2] = fy[j*3+2];
        } else {
            is[tid] = -1;
            rels[tid][0] = rels[tid][1] = rels[tid][2] = 0.0f;
            fys[tid][0] = fys[tid][1] = fys[tid][2] = 0.0f;
        }
    }
    b2s[tid] = b2[tid];
    __syncthreads();

    // ---- layer 1: h1 = gelu(rel @ W1 + b1) -> A-tile (swizzled bf16) ----
    {
        int u  = tid & 127;
        int e0 = tid >> 7;
        float w0 = W1[u], w1 = W1[128 + u], w2 = W1[256 + u], bb = b1[u];
        #pragma unroll
        for (int r = 0; r < 32; ++r) {
            int e = e0 + 2 * r;
            float pre = fmaf(rels[e][0], w0, fmaf(rels[e][1], w1, fmaf(rels[e][2], w2, bb)));
            g2s[(e * 128 + u) ^ ((e & 7) << 3)] = (__bf16)gelu_tanh(pre);
        }
    }
    __syncthreads();

    // ---- layer 2 MFMA: [64 x 128] @ [128 x 256]; wave w owns cols [64w, 64w+64) ----
    const int w    = tid >> 6;
    const int lane = tid & 63;
    const int l15  = lane & 15;
    const int h    = lane >> 4;

    f32x4 acc[4][4];
    #pragma unroll
    for (int mt = 0; mt < 4; ++mt)
        #pragma unroll
        for (int nt = 0; nt < 4; ++nt)
            acc[mt][nt] = (f32x4){0.0f, 0.0f, 0.0f, 0.0f};

    #pragma unroll
    for (int ks = 0; ks < 4; ++ks) {
        int kb = ks * 32 + h * 8;
        bf16x8 af[4], bfr[4];
        #pragma unroll
        for (int mt = 0; mt < 4; ++mt) {
            int row = mt * 16 + l15;
            af[mt] = *(const bf16x8*)&g2s[(row * 128 + kb) ^ ((row & 7) << 3)];
        }
        #pragma unroll
        for (int nt = 0; nt < 4; ++nt) {
            int u = w * 64 + nt * 16 + l15;
            bfr[nt] = *(const bf16x8*)&w2t[u * 128 + kb];   // L2-resident
        }
        #pragma unroll
        for (int mt = 0; mt < 4; ++mt)
            #pragma unroll
            for (int nt = 0; nt < 4; ++nt)
                acc[mt][nt] = __builtin_amdgcn_mfma_f32_16x16x32_bf16(af[mt], bfr[nt], acc[mt][nt], 0, 0, 0);
    }
    __syncthreads();   // A-tile reads complete; g2s may be overwritten

    // ---- epilogue: g2 = gelu(h2 + b2) -> LDS [e][u] (swizzled bf16) ----
    #pragma unroll
    for (int nt = 0; nt < 4; ++nt) {
        int u = w * 64 + nt * 16 + l15;
        float b2u = b2s[u];
        #pragma unroll
        for (int mt = 0; mt < 4; ++mt) {
            #pragma unroll
            for (int rg = 0; rg < 4; ++rg) {
                int e = mt * 16 + h * 4 + rg;
                float g = gelu_tanh(acc[mt][nt][rg] + b2u);
                g2s[(e * 256 + u) ^ ((e & 7) << 3)] = (__bf16)g;
            }
        }
    }
    __syncthreads();

    // ---- layer 3 MFMA: [64 x 256] @ [256 x 16(pad 3)]; wave w does K-slice [64w, 64w+64) ----
    f32x4 acc3[4];
    #pragma unroll
    for (int mt = 0; mt < 4; ++mt) acc3[mt] = (f32x4){0.0f, 0.0f, 0.0f, 0.0f};

    #pragma unroll
    for (int ks = 0; ks < 2; ++ks) {
        int u0 = w * 64 + ks * 32 + h * 8;
        bf16x8 b3f = *(const bf16x8*)&w3t[l15 * 256 + u0];
        #pragma unroll
        for (int mt = 0; mt < 4; ++mt) {
            int e = mt * 16 + l15;
            bf16x8 a3 = *(const bf16x8*)&g2s[(e * 256 + u0) ^ ((e & 7) << 3)];
            acc3[mt] = __builtin_amdgcn_mfma_f32_16x16x32_bf16(a3, b3f, acc3[mt], 0, 0, 0);
        }
    }
    if (l15 < 3) {
        #pragma unroll
        for (int mt = 0; mt < 4; ++mt)
            #pragma unroll
            for (int rg = 0; rg < 4; ++rg)
                out3w[w][mt * 16 + h * 4 + rg][l15] = acc3[mt][rg];
    }
    __syncthreads();

    // ---- combine wave partials, apply b3 and f_y ----
    if (tid < 192) {
        int e = tid / 3, d = tid - 3 * (tid / 3);
        float s = out3w[0][e][d] + out3w[1][e][d] + out3w[2][e][d] + out3w[3][e][d];
        msg3[e][d] = (s + b3[d]) * fys[e][d];
    }
    __syncthreads();

    // ---- segmented sum over sorted x_index: one atomic triple per distinct i ----
    if (tid < 64) {
        int i = is[tid];
        bool leader = (i >= 0) && (tid == 0 || is[tid - 1] != i);
        if (leader) {
            float s0 = 0.0f, s1 = 0.0f, s2 = 0.0f;
            int j = tid;
            while (j < 64 && is[j] == i) {
                s0 += msg3[j][0]; s1 += msg3[j][1]; s2 += msg3[j][2]; ++j;
            }
            unsafeAtomicAdd(&out[i*3+0], s0);
            unsafeAtomicAdd(&out[i*3+1], s1);
            unsafeAtomicAdd(&out[i*3+2], s2);
        }
    }
}

// out[i] /= max(cnt_i, 1); cnt via binary search on sorted x_index
__global__ void finalize_div(float* __restrict__ out, const int* __restrict__ xidx,
                             int E, int nx) {
    int i = blockIdx.x * blockDim.x + threadIdx.x;
    if (i >= nx) return;
    int lo = 0, hi = E;
    while (lo < hi) { int mid = (lo + hi) >> 1; if (xidx[mid] < i) lo = mid + 1; else hi = mid; }
    int start = lo;
    hi = E;
    while (lo < hi) { int mid = (lo + hi) >> 1; if (xidx[mid] < i + 1) lo = mid + 1; else hi = mid; }
    int cnt = lo - start;
    float inv = 1.0f / (float)(cnt > 1 ? cnt : 1);
    out[i*3+0] *= inv;
    out[i*3+1] *= inv;
    out[i*3+2] *= inv;
}

extern "C" void kernel_launch(void* const* d_in, const int* in_sizes, int n_in,
                              void* d_out, int out_size, void* d_ws, size_t ws_size,
                              hipStream_t stream) {
    const float* y   = (const float*)d_in[0];
    const float* x   = (const float*)d_in[1];
    const float* fyp = (const float*)d_in[2];
    const int*   nbr = (const int*)d_in[3];
    const int*   xix = (const int*)d_in[4];
    const float* W1  = (const float*)d_in[5];
    const float* b1  = (const float*)d_in[6];
    const float* W2  = (const float*)d_in[7];
    const float* b2  = (const float*)d_in[8];
    const float* W3  = (const float*)d_in[9];
    const float* b3  = (const float*)d_in[10];
    float* out = (float*)d_out;

    int E  = in_sizes[3];
    int nx = in_sizes[1] / 3;
    __bf16* w2t = (__bf16*)d_ws;                       // 32768 bf16 = 64KB
    __bf16* w3t = (__bf16*)((char*)d_ws + 65536);      // 4096 bf16 = 8KB

    hipMemsetAsync(d_out, 0, (size_t)out_size * sizeof(float), stream);
    prep_weights<<<144, 256, 0, stream>>>(W2, W3, w2t, w3t);

    int ntiles = (E + 63) / 64;
    edge_mlp<<<ntiles, 256, 0, stream>>>(y, x, fyp, nbr, xix, W1, b1, w2t, b2, w3t, b3, out, E);

    finalize_div<<<(nx + 255) / 256, 256, 0, stream>>>(out, xix, E, nx);
}